// Round 1
// baseline (447.498 us; speedup 1.0000x reference)
//
#include <hip/hip_runtime.h>
#include <math.h>

#define B_ 2
#define S_ 2048
#define D_ 768
#define H_ 12
#define HD_ 64
#define KKEEP 614            // max(1, int(0.3*2048))
#define M_ (B_*S_)           // 4096
#define KD_ 768
#define SRW 2072             // scB row stride in ushorts (4144B rows, 16B aligned)

typedef __attribute__((ext_vector_type(8))) short bf8;   // 8 bf16 = 4 VGPR (MFMA A/B frag)
typedef __attribute__((ext_vector_type(4))) float f4;    // MFMA 16x16 C/D frag

__device__ __forceinline__ unsigned short f2bf(float f) {   // RNE fp32->bf16
    unsigned u = __float_as_uint(f);
    u += 0x7FFF + ((u >> 16) & 1);
    return (unsigned short)(u >> 16);
}
__device__ __forceinline__ float bf2f(unsigned short h) {
    return __uint_as_float((unsigned)h << 16);
}
// fp32 -> orderable-u16 (bf16-RNE in orderable space; tie direction differs from
// value-space RNE only on exact half-ulp ties -- numerically irrelevant)
__device__ __forceinline__ unsigned f2ord16(float f) {
    unsigned u = __float_as_uint(f);
    unsigned o32 = u ^ ((unsigned)((int)u >> 31) | 0x80000000u);
    return (o32 + 0x7FFFu + ((o32 >> 16) & 1u)) >> 16;
}
// orderable-u16 -> fp32 (exact bf16 value)
__device__ __forceinline__ float ord16_to_f(unsigned o16) {
    unsigned o = o16 << 16;
    unsigned mask = 0x80000000u | ~(unsigned)((int)o >> 31);
    return __uint_as_float((o ^ mask) & 0xFFFF0000u);
}

// async global->LDS, 16B per lane (dwordx4). LDS dest must be linear:
// wave-uniform base + lane*16 -- caller guarantees that layout.
__device__ __forceinline__ void gload16(const unsigned short* g, unsigned short* l) {
    __builtin_amdgcn_global_load_lds(
        (const __attribute__((address_space(1))) unsigned int*)(const void*)g,
        (__attribute__((address_space(3))) unsigned int*)(void*)l,
        16, 0, 0);
}

// fp32 -> (bf16 hi, bf16 lo) planes
__global__ void split_kernel(const float* __restrict__ src,
                             unsigned short* __restrict__ hi,
                             unsigned short* __restrict__ lo, int n) {
    int i = blockIdx.x * blockDim.x + threadIdx.x;
    if (i >= n) return;
    float f = src[i];
    unsigned short h = f2bf(f);
    hi[i] = h;
    lo[i] = f2bf(f - bf2f(h));
}

// 4 weight matrices -> concatenated hi/lo planes [4][768*768]; y selects source
__global__ void split_w_kernel(const float* __restrict__ w0, const float* __restrict__ w1,
                               const float* __restrict__ w2, const float* __restrict__ w3,
                               unsigned short* __restrict__ hi,
                               unsigned short* __restrict__ lo) {
    const int which = blockIdx.y;
    const float* src = which == 0 ? w0 : (which == 1 ? w1 : (which == 2 ? w2 : w3));
    int i = blockIdx.x * blockDim.x + threadIdx.x;          // 0 .. 768*768-1
    size_t o = (size_t)which * (D_ * D_) + i;
    float f = src[i];
    unsigned short h = f2bf(f);
    hi[o] = h;
    lo[o] = f2bf(f - bf2f(h));
}

// Fused Q/K/V projection: C[m][n] = sum_k x[m][k]*Wcat[n][k] + bias, split-bf16
// (3 MFMA/product). m97-style structure: 128x128 tile, 4 waves (2x2 quadrants of
// 64x64), BK=32, global_load_lds(16B) staging, 2 barriers per K-step.
// grid.y in [0,18): which = y/6.
//   which 0 (Q): BHSD hi+lo, PRE-SCALED by 0.125 (fold softmax scale here)
//   which 1 (K): BHSD hi     which 2 (V): BHDS hi
__global__ __launch_bounds__(256)
void gemm_qkv(const unsigned short* __restrict__ Ahi, const unsigned short* __restrict__ Alo,
              const unsigned short* __restrict__ Wch, const unsigned short* __restrict__ Wcl,
              const float* __restrict__ bq, const float* __restrict__ bk,
              const float* __restrict__ bv,
              unsigned short* __restrict__ Qh, unsigned short* __restrict__ Ql,
              unsigned short* __restrict__ Kh, unsigned short* __restrict__ Vth) {
    __shared__ unsigned short Ah[128][32], Al[128][32], Bh[128][32], Bl[128][32];  // 32KB
    const int bm = blockIdx.x * 128, bnG = blockIdx.y * 128;
    const int which = blockIdx.y / 6;                   // 0=Q 1=K 2=V (768%128==0, no straddle)
    const int bnl = bnG - which * 768;                  // local col tile base
    const float* bias = which == 0 ? bq : (which == 1 ? bk : bv);
    const int tid = threadIdx.x, lane = tid & 63, wave = tid >> 6;
    const int col = lane & 15, quad = lane >> 4;
    const int wr = wave >> 1, wc = wave & 1;            // wave quadrant (64x64)

    f4 acc[4][4];
#pragma unroll
    for (int mi = 0; mi < 4; ++mi)
#pragma unroll
        for (int ni = 0; ni < 4; ++ni) { f4 z = {0.f,0.f,0.f,0.f}; acc[mi][ni] = z; }

    for (int kt = 0; kt < KD_; kt += 32) {
        __syncthreads();                                // prev iter's ds_reads done
#pragma unroll
        for (int c = 0; c < 2; ++c) {
            int idx = c * 256 + tid;                    // 512 chunks of 8 u16 per plane
            int row = idx >> 2, ko = (idx & 3) * 8;
            size_t ga = (size_t)(bm + row) * KD_ + kt + ko;
            size_t gb = (size_t)(bnG + row) * KD_ + kt + ko;
            gload16(&Ahi[ga], &Ah[row][ko]);
            gload16(&Alo[ga], &Al[row][ko]);
            gload16(&Wch[gb], &Bh[row][ko]);
            gload16(&Wcl[gb], &Bl[row][ko]);
        }
        __syncthreads();                                // staging landed (vmcnt drain)

        bf8 af[4][2], wf[4][2];
#pragma unroll
        for (int mi = 0; mi < 4; ++mi) {
            int r = wr * 64 + mi * 16 + col;
            af[mi][0] = *(const bf8*)&Ah[r][quad * 8];
            af[mi][1] = *(const bf8*)&Al[r][quad * 8];
        }
#pragma unroll
        for (int ni = 0; ni < 4; ++ni) {
            int r = wc * 64 + ni * 16 + col;
            wf[ni][0] = *(const bf8*)&Bh[r][quad * 8];
            wf[ni][1] = *(const bf8*)&Bl[r][quad * 8];
        }
#pragma unroll
        for (int mi = 0; mi < 4; ++mi)
#pragma unroll
            for (int ni = 0; ni < 4; ++ni) {
                acc[mi][ni] = __builtin_amdgcn_mfma_f32_16x16x32_bf16(af[mi][0], wf[ni][0], acc[mi][ni], 0, 0, 0);
                acc[mi][ni] = __builtin_amdgcn_mfma_f32_16x16x32_bf16(af[mi][1], wf[ni][0], acc[mi][ni], 0, 0, 0);
                acc[mi][ni] = __builtin_amdgcn_mfma_f32_16x16x32_bf16(af[mi][0], wf[ni][1], acc[mi][ni], 0, 0, 0);
            }
    }

    float bvv[4];
#pragma unroll
    for (int ni = 0; ni < 4; ++ni) bvv[ni] = bias[bnl + wc * 64 + ni * 16 + col];
#pragma unroll
    for (int mi = 0; mi < 4; ++mi)
#pragma unroll
        for (int ni = 0; ni < 4; ++ni)
#pragma unroll
            for (int r = 0; r < 4; ++r) {
                int m = bm + wr * 64 + mi * 16 + quad * 4 + r;   // C row = quad*4+reg
                int n = bnl + wc * 64 + ni * 16 + col;           // C col = lane&15
                float v = acc[mi][ni][r] + bvv[ni];
                if (which == 0) v *= 0.125f;                     // fold 1/sqrt(64)
                int b = m >> 11, s = m & 2047, h = n >> 6, d = n & 63;
                unsigned short hh = f2bf(v);
                if (which == 0) {
                    size_t idx = (((size_t)b * H_ + h) * S_ + s) * HD_ + d;
                    Qh[idx] = hh;
                    Ql[idx] = f2bf(v - bf2f(hh));
                } else if (which == 1) {
                    Kh[(((size_t)b * H_ + h) * S_ + s) * HD_ + d] = hh;
                } else {
                    Vth[(((size_t)b * H_ + h) * HD_ + d) * S_ + s] = hh;
                }
            }
}

// O-projection: fp32 out = AO @ Wo^T + bo (split-bf16, 3 MFMA), same structure
__global__ __launch_bounds__(256)
void gemm_o(const unsigned short* __restrict__ Ahi, const unsigned short* __restrict__ Alo,
            const unsigned short* __restrict__ Whi, const unsigned short* __restrict__ Wlo,
            const float* __restrict__ bias, float* __restrict__ outf) {
    __shared__ unsigned short Ah[128][32], Al[128][32], Bh[128][32], Bl[128][32];
    const int bm = blockIdx.x * 128, bn = blockIdx.y * 128;
    const int tid = threadIdx.x, lane = tid & 63, wave = tid >> 6;
    const int col = lane & 15, quad = lane >> 4;
    const int wr = wave >> 1, wc = wave & 1;

    f4 acc[4][4];
#pragma unroll
    for (int mi = 0; mi < 4; ++mi)
#pragma unroll
        for (int ni = 0; ni < 4; ++ni) { f4 z = {0.f,0.f,0.f,0.f}; acc[mi][ni] = z; }

    for (int kt = 0; kt < KD_; kt += 32) {
        __syncthreads();
#pragma unroll
        for (int c = 0; c < 2; ++c) {
            int idx = c * 256 + tid;
            int row = idx >> 2, ko = (idx & 3) * 8;
            size_t ga = (size_t)(bm + row) * KD_ + kt + ko;
            size_t gb = (size_t)(bn + row) * KD_ + kt + ko;
            gload16(&Ahi[ga], &Ah[row][ko]);
            gload16(&Alo[ga], &Al[row][ko]);
            gload16(&Whi[gb], &Bh[row][ko]);
            gload16(&Wlo[gb], &Bl[row][ko]);
        }
        __syncthreads();

        bf8 af[4][2], wf[4][2];
#pragma unroll
        for (int mi = 0; mi < 4; ++mi) {
            int r = wr * 64 + mi * 16 + col;
            af[mi][0] = *(const bf8*)&Ah[r][quad * 8];
            af[mi][1] = *(const bf8*)&Al[r][quad * 8];
        }
#pragma unroll
        for (int ni = 0; ni < 4; ++ni) {
            int r = wc * 64 + ni * 16 + col;
            wf[ni][0] = *(const bf8*)&Bh[r][quad * 8];
            wf[ni][1] = *(const bf8*)&Bl[r][quad * 8];
        }
#pragma unroll
        for (int mi = 0; mi < 4; ++mi)
#pragma unroll
            for (int ni = 0; ni < 4; ++ni) {
                acc[mi][ni] = __builtin_amdgcn_mfma_f32_16x16x32_bf16(af[mi][0], wf[ni][0], acc[mi][ni], 0, 0, 0);
                acc[mi][ni] = __builtin_amdgcn_mfma_f32_16x16x32_bf16(af[mi][1], wf[ni][0], acc[mi][ni], 0, 0, 0);
                acc[mi][ni] = __builtin_amdgcn_mfma_f32_16x16x32_bf16(af[mi][0], wf[ni][1], acc[mi][ni], 0, 0, 0);
            }
    }

    float bvv[4];
#pragma unroll
    for (int ni = 0; ni < 4; ++ni) bvv[ni] = bias[bn + wc * 64 + ni * 16 + col];
#pragma unroll
    for (int mi = 0; mi < 4; ++mi)
#pragma unroll
        for (int ni = 0; ni < 4; ++ni)
#pragma unroll
            for (int r = 0; r < 4; ++r) {
                int m = bm + wr * 64 + mi * 16 + quad * 4 + r;
                int n = bn + wc * 64 + ni * 16 + col;
                outf[(size_t)m * D_ + n] = acc[mi][ni][r] + bvv[ni];
            }
}

// Attention: block = 16 q rows of one (b,h); 1024 thr = 16 waves; wave owns 128 keys
// for QK, then one full row for selection. Selection count via __ballot+__popcll:
// 1 v_cmp (VALU) + s_bcnt/s_add (SALU pipe) per 64 keys, ZERO shuffle reductions.
// Packed compare trick: (hi,lo) >= (cand,0) <=> hi >= cand; (lo<<16) likewise.
__global__ __launch_bounds__(1024, 8)
void attn_kernel(const unsigned short* __restrict__ Qhi, const unsigned short* __restrict__ Qlo,
                 const unsigned short* __restrict__ Khi,
                 const unsigned short* __restrict__ Vthi,
                 unsigned short* __restrict__ AOhi, unsigned short* __restrict__ AOlo) {
    const int bid = blockIdx.x;            // 3072 = 24 bh * 128 q-tiles
    const int xcd = bid & 7, sub = (bid >> 3) % 3, tile = bid / 24;
    const int bh = xcd * 3 + sub;          // L2 locality: 3 (b,h) per XCD
    const int b = bh / H_, h = bh % H_;
    const int q0 = tile * 16;
    const int tid = threadIdx.x, lane = tid & 63, wave = tid >> 6;   // wave 0..15
    const int col = lane & 15, quad = lane >> 4;

    __shared__ __align__(16) unsigned char arena[16 * 4144];   // 66.3KB
    unsigned short* scB = (unsigned short*)arena;              // [16][SRW] u16
    float (*osum)[16][64] = (float (*)[16][64])arena;          // [16][16][64] f32 (64KB)
    __shared__ float linv[16];

    // Q A-frags direct from global: m = col = q-local, k = quad*8+j  (Q pre-scaled)
    const size_t qbase = ((size_t)bh * S_ + q0 + col) * HD_;
    bf8 qh0 = *(const bf8*)&Qhi[qbase + quad * 8];
    bf8 qh1 = *(const bf8*)&Qhi[qbase + 32 + quad * 8];
    bf8 ql0 = *(const bf8*)&Qlo[qbase + quad * 8];
    bf8 ql1 = *(const bf8*)&Qlo[qbase + 32 + quad * 8];

    // ---- QK^T (4-MFMA split): q = quad*4+r, key = wave*128 + t*16 + col ----
    const size_t kbb = (size_t)bh * S_ * HD_;
#pragma unroll 1
    for (int t = 0; t < 8; ++t) {
        const size_t kr = kbb + (size_t)(wave * 128 + t * 16 + col) * HD_;
        bf8 kh0 = *(const bf8*)&Khi[kr + quad * 8];
        bf8 kh1 = *(const bf8*)&Khi[kr + 32 + quad * 8];
        f4 a = {0.f, 0.f, 0.f, 0.f};
        a = __builtin_amdgcn_mfma_f32_16x16x32_bf16(qh0, kh0, a, 0, 0, 0);
        a = __builtin_amdgcn_mfma_f32_16x16x32_bf16(qh1, kh1, a, 0, 0, 0);
        a = __builtin_amdgcn_mfma_f32_16x16x32_bf16(ql0, kh0, a, 0, 0, 0);
        a = __builtin_amdgcn_mfma_f32_16x16x32_bf16(ql1, kh1, a, 0, 0, 0);
#pragma unroll
        for (int r = 0; r < 4; ++r)
            scB[(quad * 4 + r) * SRW + wave * 128 + t * 16 + col] =
                (unsigned short)f2ord16(a[r]);
    }
    __syncthreads();                                       // [1] transpose visible

    // ---- wave w owns row w: kv[16] packed dwords + pre-shifted kvs[16] ----
    unsigned* rowp = (unsigned*)(arena + wave * 4144);
    unsigned kv[16], kvs[16];
#pragma unroll
    for (int j = 0; j < 16; ++j) kv[j] = rowp[lane + 64 * j];   // conflict-free
#pragma unroll
    for (int j = 0; j < 16; ++j) kvs[j] = kv[j] << 16;

    // row max: u32 max's high half = max of high halves (lexicographic dominance)
    unsigned Mhi = 0, Mlo = 0;
#pragma unroll
    for (int j = 0; j < 16; ++j) {
        Mhi = kv[j]  > Mhi ? kv[j]  : Mhi;
        Mlo = kvs[j] > Mlo ? kvs[j] : Mlo;
    }
    unsigned mo = (Mhi >> 16) > (Mlo >> 16) ? (Mhi >> 16) : (Mlo >> 16);
#pragma unroll
    for (int off = 1; off < 64; off <<= 1) {
        unsigned v = __shfl_xor((int)mo, off, 64);
        mo = mo > v ? mo : v;
    }
    const float m = ord16_to_f(mo);

    // ---- threshold: largest T with count(>=T) >= KKEEP; ballot+popcount ----
    unsigned T = 0;
#pragma unroll 1
    for (int bit = 15; bit >= 0; --bit) {
        unsigned candh = (T | (1u << bit)) << 16;
        int cnt = 0;
#pragma unroll
        for (int j = 0; j < 16; ++j) {
            cnt += __popcll(__ballot(kv[j]  >= candh));    // hi halves
            cnt += __popcll(__ballot(kvs[j] >= candh));    // lo halves
        }
        if (cnt >= KKEEP) T |= (1u << bit);
    }

    // ---- weights: w = exp(s-m) if key >= T else 0; bf16 packed write-back ----
    float ls = 0.f;
#pragma unroll 1
    for (int j = 0; j < 16; ++j) {
        unsigned lo16 = kv[j] & 0xFFFFu;
        unsigned hi16 = kv[j] >> 16;
        float wl = __expf(ord16_to_f(lo16) - m);
        float wh = __expf(ord16_to_f(hi16) - m);
        wl = (lo16 >= T) ? wl : 0.f;
        wh = (hi16 >= T) ? wh : 0.f;
        ls += wl + wh;
        rowp[lane + 64 * j] = (unsigned)f2bf(wl) | ((unsigned)f2bf(wh) << 16);
    }
#pragma unroll
    for (int off = 1; off < 64; off <<= 1) ls += __shfl_xor(ls, off, 64);
    if (lane == 0) linv[wave] = 1.f / ls;
    __syncthreads();                                       // [2] weights + linv visible

    // ---- PV: A-frags (P) from scB via b128; B-frags (V^T) from global ----
    f4 od[4];
#pragma unroll
    for (int dt = 0; dt < 4; ++dt) { f4 z = {0.f,0.f,0.f,0.f}; od[dt] = z; }
    const size_t vbb = (size_t)bh * HD_ * S_;
#pragma unroll 1
    for (int c = 0; c < 4; ++c) {
        bf8 ph = *(const bf8*)&scB[col * SRW + wave * 128 + c * 32 + quad * 8];
        const size_t sbase = (size_t)(wave * 128 + c * 32 + quad * 8);
#pragma unroll
        for (int dt = 0; dt < 4; ++dt) {
            bf8 vh = *(const bf8*)&Vthi[vbb + (size_t)(dt * 16 + col) * S_ + sbase];
            od[dt] = __builtin_amdgcn_mfma_f32_16x16x32_bf16(ph, vh, od[dt], 0, 0, 0);
        }
    }
    __syncthreads();                                       // [3] all scB reads done
#pragma unroll
    for (int dt = 0; dt < 4; ++dt)
#pragma unroll
        for (int r = 0; r < 4; ++r)
            osum[wave][quad * 4 + r][dt * 16 + col] = od[dt][r];
    __syncthreads();                                       // [4] partials visible

    // ---- final: 1024 threads cover 16x64 (q,d); sum 16 partials, emit planes ----
    {
        int q = tid >> 6, d = tid & 63;
        float s = 0.f;
#pragma unroll
        for (int w = 0; w < 16; ++w) s += osum[w][q][d];
        s *= linv[q];
        size_t idx = ((size_t)b * S_ + q0 + q) * D_ + h * HD_ + d;
        unsigned short hh = f2bf(s);
        AOhi[idx] = hh;
        AOlo[idx] = f2bf(s - bf2f(hh));
    }
}

extern "C" void kernel_launch(void* const* d_in, const int* in_sizes, int n_in,
                              void* d_out, int out_size, void* d_ws, size_t ws_size,
                              hipStream_t stream) {
    const float* x  = (const float*)d_in[0];
    const float* Wq = (const float*)d_in[1];
    const float* bq = (const float*)d_in[2];
    const float* Wk = (const float*)d_in[3];
    const float* bk = (const float*)d_in[4];
    const float* Wv = (const float*)d_in[5];
    const float* bv = (const float*)d_in[6];
    const float* Wo = (const float*)d_in[7];
    const float* bo = (const float*)d_in[8];
    float* out = (float*)d_out;

    const size_t NP = (size_t)M_ * D_;      // 3,145,728 elems
    const size_t NW = (size_t)D_ * D_;      // 589,824 elems
    unsigned short* p = (unsigned short*)d_ws;
    unsigned short* xhi = p;  p += NP;
    unsigned short* xlo = p;  p += NP;
    unsigned short* Wch = p;  p += 4 * NW;   // concatenated [Wq|Wk|Wv|Wo] hi
    unsigned short* Wcl = p;  p += 4 * NW;   // concatenated lo
    unsigned short* Qh  = p;  p += NP;  unsigned short* Ql  = p;  p += NP;
    unsigned short* Kh  = p;  p += NP;
    unsigned short* Vth = p;  p += NP;
    // AO planes alias x planes (x dead after the projections)
    unsigned short* AOh = xhi;
    unsigned short* AOl = xlo;

    split_kernel<<<(int)(NP / 256), 256, 0, stream>>>(x, xhi, xlo, (int)NP);
    {
        dim3 gw((unsigned)(NW / 256), 4);
        split_w_kernel<<<gw, 256, 0, stream>>>(Wq, Wk, Wv, Wo, Wch, Wcl);
    }

    {
        dim3 g(M_ / 128, 18);               // 3 x 768/128 column tiles
        gemm_qkv<<<g, 256, 0, stream>>>(xhi, xlo, Wch, Wcl, bq, bk, bv,
                                        Qh, Ql, Kh, Vth);
    }

    attn_kernel<<<(S_ / 16) * B_ * H_, 1024, 0, stream>>>(Qh, Ql, Kh, Vth, AOh, AOl);

    {
        dim3 g(M_ / 128, D_ / 128);
        gemm_o<<<g, 256, 0, stream>>>(AOh, AOl, Wch + 3 * NW, Wcl + 3 * NW, bo, out);
    }
}

// Round 3
// 407.621 us; speedup vs baseline: 1.0978x; 1.0978x over previous
//
#include <hip/hip_runtime.h>
#include <math.h>

#define B_ 2
#define S_ 2048
#define D_ 768
#define H_ 12
#define HD_ 64
#define KKEEP 614            // max(1, int(0.3*2048))
#define M_ (B_*S_)           // 4096
#define KD_ 768
#define SRW 2072             // scB row stride in ushorts (4144B rows, 16B aligned)

typedef __attribute__((ext_vector_type(8))) short bf8;   // 8 bf16 = 4 VGPR (MFMA A/B frag)
typedef __attribute__((ext_vector_type(4))) float f4;    // MFMA 16x16 C/D frag

__device__ __forceinline__ unsigned short f2bf(float f) {   // RNE fp32->bf16
    unsigned u = __float_as_uint(f);
    u += 0x7FFF + ((u >> 16) & 1);
    return (unsigned short)(u >> 16);
}
__device__ __forceinline__ float bf2f(unsigned short h) {
    return __uint_as_float((unsigned)h << 16);
}
// fp32 -> orderable-u16 (bf16-RNE in orderable space; tie direction differs from
// value-space RNE only on exact half-ulp ties -- numerically irrelevant)
__device__ __forceinline__ unsigned f2ord16(float f) {
    unsigned u = __float_as_uint(f);
    unsigned o32 = u ^ ((unsigned)((int)u >> 31) | 0x80000000u);
    return (o32 + 0x7FFFu + ((o32 >> 16) & 1u)) >> 16;
}
// orderable-u16 -> fp32 (exact bf16 value)
__device__ __forceinline__ float ord16_to_f(unsigned o16) {
    unsigned o = o16 << 16;
    unsigned mask = 0x80000000u | ~(unsigned)((int)o >> 31);
    return __uint_as_float((o ^ mask) & 0xFFFF0000u);
}

// fp32 -> (bf16 hi, bf16 lo) planes
__global__ void split_kernel(const float* __restrict__ src,
                             unsigned short* __restrict__ hi,
                             unsigned short* __restrict__ lo, int n) {
    int i = blockIdx.x * blockDim.x + threadIdx.x;
    if (i >= n) return;
    float f = src[i];
    unsigned short h = f2bf(f);
    hi[i] = h;
    lo[i] = f2bf(f - bf2f(h));
}

// 4 weight matrices -> concatenated hi/lo planes [4][768*768]; y selects source
__global__ void split_w_kernel(const float* __restrict__ w0, const float* __restrict__ w1,
                               const float* __restrict__ w2, const float* __restrict__ w3,
                               unsigned short* __restrict__ hi,
                               unsigned short* __restrict__ lo) {
    const int which = blockIdx.y;
    const float* src = which == 0 ? w0 : (which == 1 ? w1 : (which == 2 ? w2 : w3));
    int i = blockIdx.x * blockDim.x + threadIdx.x;          // 0 .. 768*768-1
    size_t o = (size_t)which * (D_ * D_) + i;
    float f = src[i];
    unsigned short h = f2bf(f);
    hi[o] = h;
    lo[o] = f2bf(f - bf2f(h));
}

// Fused Q/K/V projection: C[m][n] = sum_k x[m][k]*Wcat[n][k] + bias, split-bf16
// (3 MFMA/product). Tile 128(M) x 64(N); grid.y in [0,36): which = y/12.
//   which 0 (Q): BHSD hi+lo, PRE-SCALED by 0.125*log2(e) (fold softmax scale AND
//                exp->exp2 conversion here; top-k invariant under positive scale)
//   which 1 (K): BHSD hi     which 2 (V): BHDS hi
__global__ __launch_bounds__(256)
void gemm_qkv(const unsigned short* __restrict__ Ahi, const unsigned short* __restrict__ Alo,
              const unsigned short* __restrict__ Wch, const unsigned short* __restrict__ Wcl,
              const float* __restrict__ bq, const float* __restrict__ bk,
              const float* __restrict__ bv,
              unsigned short* __restrict__ Qh, unsigned short* __restrict__ Ql,
              unsigned short* __restrict__ Kh, unsigned short* __restrict__ Vth) {
    __shared__ unsigned short Ah[128][32], Al[128][32], Bh[64][32], Bl[64][32];  // 24KB
    const int bm = blockIdx.x * 128, bnG = blockIdx.y * 64;
    const int which = blockIdx.y / 12;                  // 0=Q 1=K 2=V
    const int bn = bnG - which * 768;                   // local col tile base
    const float* bias = which == 0 ? bq : (which == 1 ? bk : bv);
    const int tid = threadIdx.x, lane = tid & 63, wave = tid >> 6;
    const int col = lane & 15, quad = lane >> 4;

    f4 acc[2][4];
#pragma unroll
    for (int mi = 0; mi < 2; ++mi)
#pragma unroll
        for (int ni = 0; ni < 4; ++ni) { f4 z = {0.f,0.f,0.f,0.f}; acc[mi][ni] = z; }

    for (int kt = 0; kt < KD_; kt += 32) {
        __syncthreads();
#pragma unroll
        for (int c = 0; c < 2; ++c) {
            int idx = c * 256 + tid;
            int row = idx >> 2, ko = (idx & 3) * 8;
            *(uint4*)&Ah[row][ko] = *(const uint4*)&Ahi[(size_t)(bm + row) * KD_ + kt + ko];
            *(uint4*)&Al[row][ko] = *(const uint4*)&Alo[(size_t)(bm + row) * KD_ + kt + ko];
        }
        {
            int row = tid >> 2, ko = (tid & 3) * 8;
            *(uint4*)&Bh[row][ko] = *(const uint4*)&Wch[(size_t)(bnG + row) * KD_ + kt + ko];
            *(uint4*)&Bl[row][ko] = *(const uint4*)&Wcl[(size_t)(bnG + row) * KD_ + kt + ko];
        }
        __syncthreads();

        bf8 af[2][2], wf[4][2];
#pragma unroll
        for (int mi = 0; mi < 2; ++mi) {
            int r = wave * 32 + mi * 16 + col;
            af[mi][0] = *(const bf8*)&Ah[r][quad * 8];
            af[mi][1] = *(const bf8*)&Al[r][quad * 8];
        }
#pragma unroll
        for (int ni = 0; ni < 4; ++ni) {
            int r = ni * 16 + col;
            wf[ni][0] = *(const bf8*)&Bh[r][quad * 8];
            wf[ni][1] = *(const bf8*)&Bl[r][quad * 8];
        }
#pragma unroll
        for (int mi = 0; mi < 2; ++mi)
#pragma unroll
            for (int ni = 0; ni < 4; ++ni) {
                acc[mi][ni] = __builtin_amdgcn_mfma_f32_16x16x32_bf16(af[mi][0], wf[ni][0], acc[mi][ni], 0, 0, 0);
                acc[mi][ni] = __builtin_amdgcn_mfma_f32_16x16x32_bf16(af[mi][1], wf[ni][0], acc[mi][ni], 0, 0, 0);
                acc[mi][ni] = __builtin_amdgcn_mfma_f32_16x16x32_bf16(af[mi][0], wf[ni][1], acc[mi][ni], 0, 0, 0);
            }
    }

    float bvv[4];
#pragma unroll
    for (int ni = 0; ni < 4; ++ni) bvv[ni] = bias[bn + ni * 16 + col];
#pragma unroll
    for (int mi = 0; mi < 2; ++mi)
#pragma unroll
        for (int ni = 0; ni < 4; ++ni)
#pragma unroll
            for (int r = 0; r < 4; ++r) {
                int m = bm + wave * 32 + mi * 16 + quad * 4 + r;  // C row = quad*4+reg
                int n = bn + ni * 16 + col;                       // C col = lane&15
                float v = acc[mi][ni][r] + bvv[ni];
                if (which == 0) v *= 0.18033688f;                 // 1/sqrt(64) * log2(e)
                int b = m >> 11, s = m & 2047, h = n >> 6, d = n & 63;
                unsigned short hh = f2bf(v);
                if (which == 0) {
                    size_t idx = (((size_t)b * H_ + h) * S_ + s) * HD_ + d;
                    Qh[idx] = hh;
                    Ql[idx] = f2bf(v - bf2f(hh));
                } else if (which == 1) {
                    Kh[(((size_t)b * H_ + h) * S_ + s) * HD_ + d] = hh;
                } else {
                    Vth[(((size_t)b * H_ + h) * HD_ + d) * S_ + s] = hh;
                }
            }
}

// O-projection: fp32 out = AO @ Wo^T + bo (split-bf16, 3 MFMA)
__global__ __launch_bounds__(256)
void gemm_o(const unsigned short* __restrict__ Ahi, const unsigned short* __restrict__ Alo,
            const unsigned short* __restrict__ Whi, const unsigned short* __restrict__ Wlo,
            const float* __restrict__ bias, float* __restrict__ outf) {
    __shared__ unsigned short Ah[128][32], Al[128][32], Bh[64][32], Bl[64][32];
    const int bm = blockIdx.x * 128, bn = blockIdx.y * 64;
    const int tid = threadIdx.x, lane = tid & 63, wave = tid >> 6;
    const int col = lane & 15, quad = lane >> 4;

    f4 acc[2][4];
#pragma unroll
    for (int mi = 0; mi < 2; ++mi)
#pragma unroll
        for (int ni = 0; ni < 4; ++ni) { f4 z = {0.f,0.f,0.f,0.f}; acc[mi][ni] = z; }

    for (int kt = 0; kt < KD_; kt += 32) {
        __syncthreads();
#pragma unroll
        for (int c = 0; c < 2; ++c) {
            int idx = c * 256 + tid;
            int row = idx >> 2, ko = (idx & 3) * 8;
            *(uint4*)&Ah[row][ko] = *(const uint4*)&Ahi[(size_t)(bm + row) * KD_ + kt + ko];
            *(uint4*)&Al[row][ko] = *(const uint4*)&Alo[(size_t)(bm + row) * KD_ + kt + ko];
        }
        {
            int row = tid >> 2, ko = (tid & 3) * 8;
            *(uint4*)&Bh[row][ko] = *(const uint4*)&Whi[(size_t)(bn + row) * KD_ + kt + ko];
            *(uint4*)&Bl[row][ko] = *(const uint4*)&Wlo[(size_t)(bn + row) * KD_ + kt + ko];
        }
        __syncthreads();

        bf8 af[2][2], wf[4][2];
#pragma unroll
        for (int mi = 0; mi < 2; ++mi) {
            int r = wave * 32 + mi * 16 + col;
            af[mi][0] = *(const bf8*)&Ah[r][quad * 8];
            af[mi][1] = *(const bf8*)&Al[r][quad * 8];
        }
#pragma unroll
        for (int ni = 0; ni < 4; ++ni) {
            int r = ni * 16 + col;
            wf[ni][0] = *(const bf8*)&Bh[r][quad * 8];
            wf[ni][1] = *(const bf8*)&Bl[r][quad * 8];
        }
#pragma unroll
        for (int mi = 0; mi < 2; ++mi)
#pragma unroll
            for (int ni = 0; ni < 4; ++ni) {
                acc[mi][ni] = __builtin_amdgcn_mfma_f32_16x16x32_bf16(af[mi][0], wf[ni][0], acc[mi][ni], 0, 0, 0);
                acc[mi][ni] = __builtin_amdgcn_mfma_f32_16x16x32_bf16(af[mi][1], wf[ni][0], acc[mi][ni], 0, 0, 0);
                acc[mi][ni] = __builtin_amdgcn_mfma_f32_16x16x32_bf16(af[mi][0], wf[ni][1], acc[mi][ni], 0, 0, 0);
            }
    }

    float bvv[4];
#pragma unroll
    for (int ni = 0; ni < 4; ++ni) bvv[ni] = bias[bn + ni * 16 + col];
#pragma unroll
    for (int mi = 0; mi < 2; ++mi)
#pragma unroll
        for (int ni = 0; ni < 4; ++ni)
#pragma unroll
            for (int r = 0; r < 4; ++r) {
                int m = bm + wave * 32 + mi * 16 + quad * 4 + r;
                int n = bn + ni * 16 + col;
                outf[(size_t)m * D_ + n] = acc[mi][ni][r] + bvv[ni];
            }
}

// Attention: block = 16 q rows of one (b,h); 1024 thr = 16 waves; wave owns 128 keys
// for QK, then one full row for selection. Selection count via __ballot+__popcll.
// Threshold search: bracketing false-position (seeded near row-max, bisection on
// alternate iters for worst-case guarantee) instead of fixed 16-round binary search.
// Early exit when cnt==KKEEP: a size-K superset of the final keep-set IS the final
// keep-set, so the selected keys are identical.
// Scores are pre-scaled by log2(e) in gemm_qkv, so weights use exp2 directly.
__global__ __launch_bounds__(1024, 8)
void attn_kernel(const unsigned short* __restrict__ Qhi, const unsigned short* __restrict__ Qlo,
                 const unsigned short* __restrict__ Khi,
                 const unsigned short* __restrict__ Vthi,
                 unsigned short* __restrict__ AOhi, unsigned short* __restrict__ AOlo) {
    const int bid = blockIdx.x;            // 3072 = 24 bh * 128 q-tiles
    const int xcd = bid & 7, sub = (bid >> 3) % 3, tile = bid / 24;
    const int bh = xcd * 3 + sub;          // L2 locality: 3 (b,h) per XCD
    const int b = bh / H_, h = bh % H_;
    const int q0 = tile * 16;
    const int tid = threadIdx.x, lane = tid & 63, wave = tid >> 6;   // wave 0..15
    const int col = lane & 15, quad = lane >> 4;

    __shared__ __align__(16) unsigned char arena[16 * 4144];   // 66.3KB
    unsigned short* scB = (unsigned short*)arena;              // [16][SRW] u16
    float (*osum)[16][64] = (float (*)[16][64])arena;          // [16][16][64] f32 (64KB)
    __shared__ float linv[16];

    // Q A-frags direct from global: m = col = q-local, k = quad*8+j  (Q pre-scaled)
    const size_t qbase = ((size_t)bh * S_ + q0 + col) * HD_;
    bf8 qh0 = *(const bf8*)&Qhi[qbase + quad * 8];
    bf8 qh1 = *(const bf8*)&Qhi[qbase + 32 + quad * 8];
    bf8 ql0 = *(const bf8*)&Qlo[qbase + quad * 8];
    bf8 ql1 = *(const bf8*)&Qlo[qbase + 32 + quad * 8];

    // ---- QK^T (4-MFMA split): q = quad*4+r, key = wave*128 + t*16 + col ----
    // unroll 2: pipeline the L2-resident K loads across iterations
    const size_t kbb = (size_t)bh * S_ * HD_;
#pragma unroll 2
    for (int t = 0; t < 8; ++t) {
        const size_t kr = kbb + (size_t)(wave * 128 + t * 16 + col) * HD_;
        bf8 kh0 = *(const bf8*)&Khi[kr + quad * 8];
        bf8 kh1 = *(const bf8*)&Khi[kr + 32 + quad * 8];
        f4 a = {0.f, 0.f, 0.f, 0.f};
        a = __builtin_amdgcn_mfma_f32_16x16x32_bf16(qh0, kh0, a, 0, 0, 0);
        a = __builtin_amdgcn_mfma_f32_16x16x32_bf16(qh1, kh1, a, 0, 0, 0);
        a = __builtin_amdgcn_mfma_f32_16x16x32_bf16(ql0, kh0, a, 0, 0, 0);
        a = __builtin_amdgcn_mfma_f32_16x16x32_bf16(ql1, kh1, a, 0, 0, 0);
#pragma unroll
        for (int r = 0; r < 4; ++r)
            scB[(quad * 4 + r) * SRW + wave * 128 + t * 16 + col] =
                (unsigned short)f2ord16(a[r]);
    }
    __syncthreads();                                       // [1] transpose visible

    // ---- wave w owns row w: kv[16] packed dwords + pre-shifted kvs[16] ----
    unsigned* rowp = (unsigned*)(arena + wave * 4144);
    unsigned kv[16], kvs[16];
#pragma unroll
    for (int j = 0; j < 16; ++j) kv[j] = rowp[lane + 64 * j];   // conflict-free
#pragma unroll
    for (int j = 0; j < 16; ++j) kvs[j] = kv[j] << 16;

    // row max: u32 max's high half = max of high halves (lexicographic dominance)
    unsigned Mhi = 0, Mlo = 0;
#pragma unroll
    for (int j = 0; j < 16; ++j) {
        Mhi = kv[j]  > Mhi ? kv[j]  : Mhi;
        Mlo = kvs[j] > Mlo ? kvs[j] : Mlo;
    }
    unsigned mo = (Mhi >> 16) > (Mlo >> 16) ? (Mhi >> 16) : (Mlo >> 16);
#pragma unroll
    for (int off = 1; off < 64; off <<= 1) {
        unsigned v = __shfl_xor((int)mo, off, 64);
        mo = mo > v ? mo : v;
    }
    const float m = ord16_to_f(mo);

    // ---- threshold: largest T with count(>=T) >= KKEEP (or any T with exact
    //      count == KKEEP: same keep-set). Bracketed false-position search. ----
    unsigned lo = 0, hi = mo + 1;          // invariant: cnt(lo)>=K, cnt(hi)<K
    int cnt_lo = 2048, cnt_hi = 0;
    unsigned T;
    // seed: top-k threshold typically a few exponent steps below row max
    unsigned probe = (mo > 0x200u) ? (mo - 0x200u) : 1u;
    int iter = 0;
    while (true) {
        unsigned candh = probe << 16;
        int cnt = 0;
#pragma unroll
        for (int j = 0; j < 16; ++j) {
            cnt += __popcll(__ballot(kv[j]  >= candh));    // hi halves
            cnt += __popcll(__ballot(kvs[j] >= candh));    // lo halves
        }
        if (cnt == KKEEP) { T = probe; break; }            // exact: same keep-set
        if (cnt > KKEEP) { lo = probe; cnt_lo = cnt; }
        else             { hi = probe; cnt_hi = cnt; }
        if (hi - lo <= 1) { T = lo; break; }
        ++iter;
        if (iter & 1) {
            probe = (lo + hi) >> 1;                        // guaranteed shrink
        } else {
            float f = (float)(cnt_lo - KKEEP) / (float)(cnt_lo - cnt_hi);
            unsigned step = (unsigned)((float)(hi - lo) * f);
            probe = lo + step;
            if (probe <= lo) probe = lo + 1;
            if (probe >= hi) probe = hi - 1;
        }
    }

    // ---- weights: w = exp2(s-m) if key >= T else 0; bf16 packed write-back ----
    float ls = 0.f;
#pragma unroll 1
    for (int j = 0; j < 16; ++j) {
        unsigned lo16 = kv[j] & 0xFFFFu;
        unsigned hi16 = kv[j] >> 16;
        float wl = __builtin_amdgcn_exp2f(ord16_to_f(lo16) - m);
        float wh = __builtin_amdgcn_exp2f(ord16_to_f(hi16) - m);
        wl = (lo16 >= T) ? wl : 0.f;
        wh = (hi16 >= T) ? wh : 0.f;
        ls += wl + wh;
        rowp[lane + 64 * j] = (unsigned)f2bf(wl) | ((unsigned)f2bf(wh) << 16);
    }
#pragma unroll
    for (int off = 1; off < 64; off <<= 1) ls += __shfl_xor(ls, off, 64);
    if (lane == 0) linv[wave] = 1.f / ls;
    __syncthreads();                                       // [2] weights + linv visible

    // ---- PV: A-frags (P) from scB via b128; B-frags (V^T) from global ----
    f4 od[4];
#pragma unroll
    for (int dt = 0; dt < 4; ++dt) { f4 z = {0.f,0.f,0.f,0.f}; od[dt] = z; }
    const size_t vbb = (size_t)bh * HD_ * S_;
#pragma unroll 1
    for (int c = 0; c < 4; ++c) {
        bf8 ph = *(const bf8*)&scB[col * SRW + wave * 128 + c * 32 + quad * 8];
        const size_t sbase = (size_t)(wave * 128 + c * 32 + quad * 8);
#pragma unroll
        for (int dt = 0; dt < 4; ++dt) {
            bf8 vh = *(const bf8*)&Vthi[vbb + (size_t)(dt * 16 + col) * S_ + sbase];
            od[dt] = __builtin_amdgcn_mfma_f32_16x16x32_bf16(ph, vh, od[dt], 0, 0, 0);
        }
    }
    __syncthreads();                                       // [3] all scB reads done
#pragma unroll
    for (int dt = 0; dt < 4; ++dt)
#pragma unroll
        for (int r = 0; r < 4; ++r)
            osum[wave][quad * 4 + r][dt * 16 + col] = od[dt][r];
    __syncthreads();                                       // [4] partials visible

    // ---- final: 1024 threads cover 16x64 (q,d); sum 16 partials, emit planes ----
    {
        int q = tid >> 6, d = tid & 63;
        float s = 0.f;
#pragma unroll
        for (int w = 0; w < 16; ++w) s += osum[w][q][d];
        s *= linv[q];
        size_t idx = ((size_t)b * S_ + q0 + q) * D_ + h * HD_ + d;
        unsigned short hh = f2bf(s);
        AOhi[idx] = hh;
        AOlo[idx] = f2bf(s - bf2f(hh));
    }
}

extern "C" void kernel_launch(void* const* d_in, const int* in_sizes, int n_in,
                              void* d_out, int out_size, void* d_ws, size_t ws_size,
                              hipStream_t stream) {
    const float* x  = (const float*)d_in[0];
    const float* Wq = (const float*)d_in[1];
    const float* bq = (const float*)d_in[2];
    const float* Wk = (const float*)d_in[3];
    const float* bk = (const float*)d_in[4];
    const float* Wv = (const float*)d_in[5];
    const float* bv = (const float*)d_in[6];
    const float* Wo = (const float*)d_in[7];
    const float* bo = (const float*)d_in[8];
    float* out = (float*)d_out;

    const size_t NP = (size_t)M_ * D_;      // 3,145,728 elems
    const size_t NW = (size_t)D_ * D_;      // 589,824 elems
    unsigned short* p = (unsigned short*)d_ws;
    unsigned short* xhi = p;  p += NP;
    unsigned short* xlo = p;  p += NP;
    unsigned short* Wch = p;  p += 4 * NW;   // concatenated [Wq|Wk|Wv|Wo] hi
    unsigned short* Wcl = p;  p += 4 * NW;   // concatenated lo
    unsigned short* Qh  = p;  p += NP;  unsigned short* Ql  = p;  p += NP;
    unsigned short* Kh  = p;  p += NP;
    unsigned short* Vth = p;  p += NP;
    // AO planes alias x planes (x dead after the projections)
    unsigned short* AOh = xhi;
    unsigned short* AOl = xlo;

    split_kernel<<<(int)(NP / 256), 256, 0, stream>>>(x, xhi, xlo, (int)NP);
    {
        dim3 gw((unsigned)(NW / 256), 4);
        split_w_kernel<<<gw, 256, 0, stream>>>(Wq, Wk, Wv, Wo, Wch, Wcl);
    }

    {
        dim3 g(M_ / 128, 36);               // 3 x 768/64 column tiles
        gemm_qkv<<<g, 256, 0, stream>>>(xhi, xlo, Wch, Wcl, bq, bk, bv,
                                        Qh, Ql, Kh, Vth);
    }

    attn_kernel<<<(S_ / 16) * B_ * H_, 1024, 0, stream>>>(Qh, Ql, Kh, Vth, AOh, AOl);

    {
        dim3 g(M_ / 128, D_ / 64);
        gemm_o<<<g, 256, 0, stream>>>(AOh, AOl, Wch + 3 * NW, Wcl + 3 * NW, bo, out);
    }
}

// Round 4
// 401.242 us; speedup vs baseline: 1.1153x; 1.0159x over previous
//
#include <hip/hip_runtime.h>
#include <math.h>

#define B_ 2
#define S_ 2048
#define D_ 768
#define H_ 12
#define HD_ 64
#define KKEEP 614            // max(1, int(0.3*2048))
#define M_ (B_*S_)           // 4096
#define KD_ 768
#define SRW 2072             // scB row stride in ushorts (4144B rows, 16B aligned)

typedef __attribute__((ext_vector_type(8))) short bf8;   // 8 bf16 = 4 VGPR (MFMA A/B frag)
typedef __attribute__((ext_vector_type(4))) float f4;    // MFMA 16x16 C/D frag

__device__ __forceinline__ unsigned short f2bf(float f) {   // RNE fp32->bf16
    unsigned u = __float_as_uint(f);
    u += 0x7FFF + ((u >> 16) & 1);
    return (unsigned short)(u >> 16);
}
__device__ __forceinline__ float bf2f(unsigned short h) {
    return __uint_as_float((unsigned)h << 16);
}
// fp32 -> orderable-u16 (bf16-RNE in orderable space; tie direction differs from
// value-space RNE only on exact half-ulp ties -- numerically irrelevant)
__device__ __forceinline__ unsigned f2ord16(float f) {
    unsigned u = __float_as_uint(f);
    unsigned o32 = u ^ ((unsigned)((int)u >> 31) | 0x80000000u);
    return (o32 + 0x7FFFu + ((o32 >> 16) & 1u)) >> 16;
}
// orderable-u16 -> fp32 (exact bf16 value)
__device__ __forceinline__ float ord16_to_f(unsigned o16) {
    unsigned o = o16 << 16;
    unsigned mask = 0x80000000u | ~(unsigned)((int)o >> 31);
    return __uint_as_float((o ^ mask) & 0xFFFF0000u);
}

// fp32 -> (bf16 hi, bf16 lo) planes
__global__ void split_kernel(const float* __restrict__ src,
                             unsigned short* __restrict__ hi,
                             unsigned short* __restrict__ lo, int n) {
    int i = blockIdx.x * blockDim.x + threadIdx.x;
    if (i >= n) return;
    float f = src[i];
    unsigned short h = f2bf(f);
    hi[i] = h;
    lo[i] = f2bf(f - bf2f(h));
}

// 4 weight matrices -> concatenated hi/lo planes [4][768*768]; y selects source
__global__ void split_w_kernel(const float* __restrict__ w0, const float* __restrict__ w1,
                               const float* __restrict__ w2, const float* __restrict__ w3,
                               unsigned short* __restrict__ hi,
                               unsigned short* __restrict__ lo) {
    const int which = blockIdx.y;
    const float* src = which == 0 ? w0 : (which == 1 ? w1 : (which == 2 ? w2 : w3));
    int i = blockIdx.x * blockDim.x + threadIdx.x;          // 0 .. 768*768-1
    size_t o = (size_t)which * (D_ * D_) + i;
    float f = src[i];
    unsigned short h = f2bf(f);
    hi[o] = h;
    lo[o] = f2bf(f - bf2f(h));
}

// Fused Q/K/V projection: C[m][n] = sum_k x[m][k]*Wcat[n][k] + bias, split-bf16
// (3 MFMA/product). Tile 128(M) x 64(N); grid.y in [0,36): which = y/12.
//   which 0 (Q): BHSD hi+lo, PRE-SCALED by 0.125*log2(e) (fold softmax scale AND
//                exp->exp2 conversion here; top-k invariant under positive scale)
//   which 1 (K): BHSD hi     which 2 (V): BHDS hi
__global__ __launch_bounds__(256)
void gemm_qkv(const unsigned short* __restrict__ Ahi, const unsigned short* __restrict__ Alo,
              const unsigned short* __restrict__ Wch, const unsigned short* __restrict__ Wcl,
              const float* __restrict__ bq, const float* __restrict__ bk,
              const float* __restrict__ bv,
              unsigned short* __restrict__ Qh, unsigned short* __restrict__ Ql,
              unsigned short* __restrict__ Kh, unsigned short* __restrict__ Vth) {
    __shared__ unsigned short Ah[128][32], Al[128][32], Bh[64][32], Bl[64][32];  // 24KB
    const int bm = blockIdx.x * 128, bnG = blockIdx.y * 64;
    const int which = blockIdx.y / 12;                  // 0=Q 1=K 2=V
    const int bn = bnG - which * 768;                   // local col tile base
    const float* bias = which == 0 ? bq : (which == 1 ? bk : bv);
    const int tid = threadIdx.x, lane = tid & 63, wave = tid >> 6;
    const int col = lane & 15, quad = lane >> 4;

    f4 acc[2][4];
#pragma unroll
    for (int mi = 0; mi < 2; ++mi)
#pragma unroll
        for (int ni = 0; ni < 4; ++ni) { f4 z = {0.f,0.f,0.f,0.f}; acc[mi][ni] = z; }

    for (int kt = 0; kt < KD_; kt += 32) {
        __syncthreads();
#pragma unroll
        for (int c = 0; c < 2; ++c) {
            int idx = c * 256 + tid;
            int row = idx >> 2, ko = (idx & 3) * 8;
            *(uint4*)&Ah[row][ko] = *(const uint4*)&Ahi[(size_t)(bm + row) * KD_ + kt + ko];
            *(uint4*)&Al[row][ko] = *(const uint4*)&Alo[(size_t)(bm + row) * KD_ + kt + ko];
        }
        {
            int row = tid >> 2, ko = (tid & 3) * 8;
            *(uint4*)&Bh[row][ko] = *(const uint4*)&Wch[(size_t)(bnG + row) * KD_ + kt + ko];
            *(uint4*)&Bl[row][ko] = *(const uint4*)&Wcl[(size_t)(bnG + row) * KD_ + kt + ko];
        }
        __syncthreads();

        bf8 af[2][2], wf[4][2];
#pragma unroll
        for (int mi = 0; mi < 2; ++mi) {
            int r = wave * 32 + mi * 16 + col;
            af[mi][0] = *(const bf8*)&Ah[r][quad * 8];
            af[mi][1] = *(const bf8*)&Al[r][quad * 8];
        }
#pragma unroll
        for (int ni = 0; ni < 4; ++ni) {
            int r = ni * 16 + col;
            wf[ni][0] = *(const bf8*)&Bh[r][quad * 8];
            wf[ni][1] = *(const bf8*)&Bl[r][quad * 8];
        }
#pragma unroll
        for (int mi = 0; mi < 2; ++mi)
#pragma unroll
            for (int ni = 0; ni < 4; ++ni) {
                acc[mi][ni] = __builtin_amdgcn_mfma_f32_16x16x32_bf16(af[mi][0], wf[ni][0], acc[mi][ni], 0, 0, 0);
                acc[mi][ni] = __builtin_amdgcn_mfma_f32_16x16x32_bf16(af[mi][1], wf[ni][0], acc[mi][ni], 0, 0, 0);
                acc[mi][ni] = __builtin_amdgcn_mfma_f32_16x16x32_bf16(af[mi][0], wf[ni][1], acc[mi][ni], 0, 0, 0);
            }
    }

    float bvv[4];
#pragma unroll
    for (int ni = 0; ni < 4; ++ni) bvv[ni] = bias[bn + ni * 16 + col];
#pragma unroll
    for (int mi = 0; mi < 2; ++mi)
#pragma unroll
        for (int ni = 0; ni < 4; ++ni)
#pragma unroll
            for (int r = 0; r < 4; ++r) {
                int m = bm + wave * 32 + mi * 16 + quad * 4 + r;  // C row = quad*4+reg
                int n = bn + ni * 16 + col;                       // C col = lane&15
                float v = acc[mi][ni][r] + bvv[ni];
                if (which == 0) v *= 0.18033688f;                 // 1/sqrt(64) * log2(e)
                int b = m >> 11, s = m & 2047, h = n >> 6, d = n & 63;
                unsigned short hh = f2bf(v);
                if (which == 0) {
                    size_t idx = (((size_t)b * H_ + h) * S_ + s) * HD_ + d;
                    Qh[idx] = hh;
                    Ql[idx] = f2bf(v - bf2f(hh));
                } else if (which == 1) {
                    Kh[(((size_t)b * H_ + h) * S_ + s) * HD_ + d] = hh;
                } else {
                    Vth[(((size_t)b * H_ + h) * HD_ + d) * S_ + s] = hh;
                }
            }
}

// O-projection: fp32 out = AO @ Wo^T + bo (split-bf16, 3 MFMA)
__global__ __launch_bounds__(256)
void gemm_o(const unsigned short* __restrict__ Ahi, const unsigned short* __restrict__ Alo,
            const unsigned short* __restrict__ Whi, const unsigned short* __restrict__ Wlo,
            const float* __restrict__ bias, float* __restrict__ outf) {
    __shared__ unsigned short Ah[128][32], Al[128][32], Bh[64][32], Bl[64][32];
    const int bm = blockIdx.x * 128, bn = blockIdx.y * 64;
    const int tid = threadIdx.x, lane = tid & 63, wave = tid >> 6;
    const int col = lane & 15, quad = lane >> 4;

    f4 acc[2][4];
#pragma unroll
    for (int mi = 0; mi < 2; ++mi)
#pragma unroll
        for (int ni = 0; ni < 4; ++ni) { f4 z = {0.f,0.f,0.f,0.f}; acc[mi][ni] = z; }

    for (int kt = 0; kt < KD_; kt += 32) {
        __syncthreads();
#pragma unroll
        for (int c = 0; c < 2; ++c) {
            int idx = c * 256 + tid;
            int row = idx >> 2, ko = (idx & 3) * 8;
            *(uint4*)&Ah[row][ko] = *(const uint4*)&Ahi[(size_t)(bm + row) * KD_ + kt + ko];
            *(uint4*)&Al[row][ko] = *(const uint4*)&Alo[(size_t)(bm + row) * KD_ + kt + ko];
        }
        {
            int row = tid >> 2, ko = (tid & 3) * 8;
            *(uint4*)&Bh[row][ko] = *(const uint4*)&Whi[(size_t)(bn + row) * KD_ + kt + ko];
            *(uint4*)&Bl[row][ko] = *(const uint4*)&Wlo[(size_t)(bn + row) * KD_ + kt + ko];
        }
        __syncthreads();

        bf8 af[2][2], wf[4][2];
#pragma unroll
        for (int mi = 0; mi < 2; ++mi) {
            int r = wave * 32 + mi * 16 + col;
            af[mi][0] = *(const bf8*)&Ah[r][quad * 8];
            af[mi][1] = *(const bf8*)&Al[r][quad * 8];
        }
#pragma unroll
        for (int ni = 0; ni < 4; ++ni) {
            int r = ni * 16 + col;
            wf[ni][0] = *(const bf8*)&Bh[r][quad * 8];
            wf[ni][1] = *(const bf8*)&Bl[r][quad * 8];
        }
#pragma unroll
        for (int mi = 0; mi < 2; ++mi)
#pragma unroll
            for (int ni = 0; ni < 4; ++ni) {
                acc[mi][ni] = __builtin_amdgcn_mfma_f32_16x16x32_bf16(af[mi][0], wf[ni][0], acc[mi][ni], 0, 0, 0);
                acc[mi][ni] = __builtin_amdgcn_mfma_f32_16x16x32_bf16(af[mi][1], wf[ni][0], acc[mi][ni], 0, 0, 0);
                acc[mi][ni] = __builtin_amdgcn_mfma_f32_16x16x32_bf16(af[mi][0], wf[ni][1], acc[mi][ni], 0, 0, 0);
            }
    }

    float bvv[4];
#pragma unroll
    for (int ni = 0; ni < 4; ++ni) bvv[ni] = bias[bn + ni * 16 + col];
#pragma unroll
    for (int mi = 0; mi < 2; ++mi)
#pragma unroll
        for (int ni = 0; ni < 4; ++ni)
#pragma unroll
            for (int r = 0; r < 4; ++r) {
                int m = bm + wave * 32 + mi * 16 + quad * 4 + r;
                int n = bn + ni * 16 + col;
                outf[(size_t)m * D_ + n] = acc[mi][ni][r] + bvv[ni];
            }
}

// Attention: block = 16 q rows of one (b,h); 1024 thr = 16 waves; wave owns 128 keys
// for QK, then one full row for selection. Selection count via __ballot+__popcll.
// Threshold search: bracketing false-position, early-exit on exact count.
// All global loads use wave-uniform SGPR base + 32-bit offsets (panels < 2^31 B).
// kv row traffic: 4x ds_read_b128 / 4x ds_write_b128 with chunk-XOR swizzle
// ((lane>>1)&3) so 64 lanes cover all 8 LDS chunk-slots (optimal 8-deep b128).
// Key<->lane assignment is position-agnostic for max/count; read addr == write
// addr, so PV's positional scB reads are unaffected.
__global__ __launch_bounds__(1024, 8)
void attn_kernel(const unsigned short* __restrict__ Qhi, const unsigned short* __restrict__ Qlo,
                 const unsigned short* __restrict__ Khi,
                 const unsigned short* __restrict__ Vthi,
                 unsigned short* __restrict__ AOhi, unsigned short* __restrict__ AOlo) {
    const int bid = blockIdx.x;            // 3072 = 24 bh * 128 q-tiles
    const int xcd = bid & 7, sub = (bid >> 3) % 3, tile = bid / 24;
    const int bh = xcd * 3 + sub;          // L2 locality: 3 (b,h) per XCD
    const int b = bh / H_, h = bh % H_;
    const int q0 = tile * 16;
    const int tid = threadIdx.x, lane = tid & 63, wave = tid >> 6;   // wave 0..15
    const int col = lane & 15, quad = lane >> 4;

    __shared__ __align__(16) unsigned char arena[16 * 4144];   // 66.3KB
    unsigned short* scB = (unsigned short*)arena;              // [16][SRW] u16
    float (*osum)[16][64] = (float (*)[16][64])arena;          // [16][16][64] f32 (64KB)
    __shared__ float linv[16];

    // Q A-frags direct from global: m = col = q-local, k = quad*8+j  (Q pre-scaled)
    const unsigned short* Qbh = Qhi + (size_t)bh * (S_ * HD_);
    const unsigned short* Qbl = Qlo + (size_t)bh * (S_ * HD_);
    const unsigned qo = (unsigned)((q0 + col) * HD_ + quad * 8);
    bf8 qh0 = *(const bf8*)&Qbh[qo];
    bf8 qh1 = *(const bf8*)&Qbh[qo + 32];
    bf8 ql0 = *(const bf8*)&Qbl[qo];
    bf8 ql1 = *(const bf8*)&Qbl[qo + 32];

    // ---- QK^T (split, 2 indep 2-chains): q = quad*4+r, key = wave*128+t*16+col ----
    const unsigned short* Kb = Khi + (size_t)bh * (S_ * HD_);
#pragma unroll 2
    for (int t = 0; t < 8; ++t) {
        const unsigned kro = (unsigned)((wave * 128 + t * 16 + col) * HD_ + quad * 8);
        bf8 kh0 = *(const bf8*)&Kb[kro];
        bf8 kh1 = *(const bf8*)&Kb[kro + 32];
        f4 z = {0.f, 0.f, 0.f, 0.f};
        f4 ah = __builtin_amdgcn_mfma_f32_16x16x32_bf16(qh0, kh0, z, 0, 0, 0);
        ah = __builtin_amdgcn_mfma_f32_16x16x32_bf16(qh1, kh1, ah, 0, 0, 0);
        f4 al = __builtin_amdgcn_mfma_f32_16x16x32_bf16(ql0, kh0, z, 0, 0, 0);
        al = __builtin_amdgcn_mfma_f32_16x16x32_bf16(ql1, kh1, al, 0, 0, 0);
        f4 a = ah + al;
#pragma unroll
        for (int r = 0; r < 4; ++r)
            scB[(quad * 4 + r) * SRW + wave * 128 + t * 16 + col] =
                (unsigned short)f2ord16(a[r]);
    }
    __syncthreads();                                       // [1] transpose visible

    // ---- wave w owns row w: kv[16] dwords via 4 swizzled ds_read_b128 ----
    unsigned* rowp = (unsigned*)(arena + wave * 4144);
    const unsigned s_swz = ((unsigned)lane >> 1) & 3u;     // chunk-slot XOR
    unsigned kv[16], kvs[16];
#pragma unroll
    for (int r = 0; r < 4; ++r) {
        uint4 v = *(const uint4*)&rowp[lane * 16 + (((unsigned)r ^ s_swz) << 2)];
        kv[r * 4 + 0] = v.x; kv[r * 4 + 1] = v.y;
        kv[r * 4 + 2] = v.z; kv[r * 4 + 3] = v.w;
    }
#pragma unroll
    for (int j = 0; j < 16; ++j) kvs[j] = kv[j] << 16;

    // row max: u32 max's high half = max of high halves (lexicographic dominance)
    unsigned Mhi = 0, Mlo = 0;
#pragma unroll
    for (int j = 0; j < 16; ++j) {
        Mhi = kv[j]  > Mhi ? kv[j]  : Mhi;
        Mlo = kvs[j] > Mlo ? kvs[j] : Mlo;
    }
    unsigned mo = (Mhi >> 16) > (Mlo >> 16) ? (Mhi >> 16) : (Mlo >> 16);
#pragma unroll
    for (int off = 1; off < 64; off <<= 1) {
        unsigned v = __shfl_xor((int)mo, off, 64);
        mo = mo > v ? mo : v;
    }
    const float m = ord16_to_f(mo);

    // ---- threshold: largest T with count(>=T) >= KKEEP (or any T with exact
    //      count == KKEEP: same keep-set). Bracketed false-position search. ----
    unsigned lo = 0, hi = mo + 1;          // invariant: cnt(lo)>=K, cnt(hi)<K
    int cnt_lo = 2048, cnt_hi = 0;
    unsigned T;
    // seed: top-k threshold typically a few exponent steps below row max
    unsigned probe = (mo > 0x200u) ? (mo - 0x200u) : 1u;
    int iter = 0;
    while (true) {
        unsigned candh = probe << 16;
        int cnt = 0;
#pragma unroll
        for (int j = 0; j < 16; ++j) {
            cnt += __popcll(__ballot(kv[j]  >= candh));    // hi halves
            cnt += __popcll(__ballot(kvs[j] >= candh));    // lo halves
        }
        if (cnt == KKEEP) { T = probe; break; }            // exact: same keep-set
        if (cnt > KKEEP) { lo = probe; cnt_lo = cnt; }
        else             { hi = probe; cnt_hi = cnt; }
        if (hi - lo <= 1) { T = lo; break; }
        ++iter;
        if (iter & 1) {
            probe = (lo + hi) >> 1;                        // guaranteed shrink
        } else {
            float f = (float)(cnt_lo - KKEEP) / (float)(cnt_lo - cnt_hi);
            unsigned step = (unsigned)((float)(hi - lo) * f);
            probe = lo + step;
            if (probe <= lo) probe = lo + 1;
            if (probe >= hi) probe = hi - 1;
        }
    }

    // ---- weights: w = exp2(s-m) if key >= T else 0; cvt_pk bf16 pack;
    //      write-back as 4 swizzled ds_write_b128 (same addrs as the reads) ----
    float ls = 0.f;
#pragma unroll
    for (int g = 0; g < 4; ++g) {
        unsigned wv[4];
#pragma unroll
        for (int u = 0; u < 4; ++u) {
            int j = g * 4 + u;
            unsigned lo16 = kv[j] & 0xFFFFu;
            unsigned hi16 = kv[j] >> 16;
            float wl = __builtin_amdgcn_exp2f(ord16_to_f(lo16) - m);
            float wh = __builtin_amdgcn_exp2f(ord16_to_f(hi16) - m);
            wl = (lo16 >= T) ? wl : 0.f;
            wh = (hi16 >= T) ? wh : 0.f;
            ls += wl + wh;
            unsigned pk;
            asm("v_cvt_pk_bf16_f32 %0, %1, %2" : "=v"(pk) : "v"(wl), "v"(wh));
            wv[u] = pk;
        }
        uint4 o; o.x = wv[0]; o.y = wv[1]; o.z = wv[2]; o.w = wv[3];
        *(uint4*)&rowp[lane * 16 + (((unsigned)g ^ s_swz) << 2)] = o;
    }
#pragma unroll
    for (int off = 1; off < 64; off <<= 1) ls += __shfl_xor(ls, off, 64);
    if (lane == 0) linv[wave] = 1.f / ls;
    __syncthreads();                                       // [2] weights + linv visible

    // ---- PV: A-frags (P) from scB via b128; B-frags (V^T) from global ----
    f4 od[4];
#pragma unroll
    for (int dt = 0; dt < 4; ++dt) { f4 z = {0.f,0.f,0.f,0.f}; od[dt] = z; }
    const unsigned short* Vb = Vthi + (size_t)bh * (HD_ * S_);
#pragma unroll 1
    for (int c = 0; c < 4; ++c) {
        bf8 ph = *(const bf8*)&scB[col * SRW + wave * 128 + c * 32 + quad * 8];
        const unsigned sb = (unsigned)(wave * 128 + c * 32 + quad * 8);
#pragma unroll
        for (int dt = 0; dt < 4; ++dt) {
            bf8 vh = *(const bf8*)&Vb[(unsigned)((dt * 16 + col) * S_) + sb];
            od[dt] = __builtin_amdgcn_mfma_f32_16x16x32_bf16(ph, vh, od[dt], 0, 0, 0);
        }
    }
    __syncthreads();                                       // [3] all scB reads done
#pragma unroll
    for (int dt = 0; dt < 4; ++dt)
#pragma unroll
        for (int r = 0; r < 4; ++r)
            osum[wave][quad * 4 + r][dt * 16 + col] = od[dt][r];
    __syncthreads();                                       // [4] partials visible

    // ---- final: 1024 threads cover 16x64 (q,d); sum 16 partials, emit planes ----
    {
        int q = tid >> 6, d = tid & 63;
        float s = 0.f;
#pragma unroll
        for (int w = 0; w < 16; ++w) s += osum[w][q][d];
        s *= linv[q];
        size_t idx = ((size_t)b * S_ + q0 + q) * D_ + h * HD_ + d;
        unsigned short hh = f2bf(s);
        AOhi[idx] = hh;
        AOlo[idx] = f2bf(s - bf2f(hh));
    }
}

extern "C" void kernel_launch(void* const* d_in, const int* in_sizes, int n_in,
                              void* d_out, int out_size, void* d_ws, size_t ws_size,
                              hipStream_t stream) {
    const float* x  = (const float*)d_in[0];
    const float* Wq = (const float*)d_in[1];
    const float* bq = (const float*)d_in[2];
    const float* Wk = (const float*)d_in[3];
    const float* bk = (const float*)d_in[4];
    const float* Wv = (const float*)d_in[5];
    const float* bv = (const float*)d_in[6];
    const float* Wo = (const float*)d_in[7];
    const float* bo = (const float*)d_in[8];
    float* out = (float*)d_out;

    const size_t NP = (size_t)M_ * D_;      // 3,145,728 elems
    const size_t NW = (size_t)D_ * D_;      // 589,824 elems
    unsigned short* p = (unsigned short*)d_ws;
    unsigned short* xhi = p;  p += NP;
    unsigned short* xlo = p;  p += NP;
    unsigned short* Wch = p;  p += 4 * NW;   // concatenated [Wq|Wk|Wv|Wo] hi
    unsigned short* Wcl = p;  p += 4 * NW;   // concatenated lo
    unsigned short* Qh  = p;  p += NP;  unsigned short* Ql  = p;  p += NP;
    unsigned short* Kh  = p;  p += NP;
    unsigned short* Vth = p;  p += NP;
    // AO planes alias x planes (x dead after the projections)
    unsigned short* AOh = xhi;
    unsigned short* AOl = xlo;

    split_kernel<<<(int)(NP / 256), 256, 0, stream>>>(x, xhi, xlo, (int)NP);
    {
        dim3 gw((unsigned)(NW / 256), 4);
        split_w_kernel<<<gw, 256, 0, stream>>>(Wq, Wk, Wv, Wo, Wch, Wcl);
    }

    {
        dim3 g(M_ / 128, 36);               // 3 x 768/64 column tiles
        gemm_qkv<<<g, 256, 0, stream>>>(xhi, xlo, Wch, Wcl, bq, bk, bv,
                                        Qh, Ql, Kh, Vth);
    }

    attn_kernel<<<(S_ / 16) * B_ * H_, 1024, 0, stream>>>(Qh, Ql, Kh, Vth, AOh, AOl);

    {
        dim3 g(M_ / 128, D_ / 64);
        gemm_o<<<g, 256, 0, stream>>>(AOh, AOl, Wch + 3 * NW, Wcl + 3 * NW, bo, out);
    }
}